// Round 15
// baseline (108.693 us; speedup 1.0000x reference)
//
#include <hip/hip_runtime.h>

// Depth-4 path signature, C=10, L=64, B=2048 — MFMA formulation (R15).
// Closed form (validated R8-R14, absmax 5.25 vs thr 12.16):
//   P_t = exclusive prefix of dx;  R_t[l] = S1[l] - P_{t+1}[l]
//   per (i,j): s2 serial Horner chain; u2_t, v2_t level-2 scalars
//   S4[ij,kl] = sum_t v2_t*(dx_t[k]*R_t[l]) + sum_t u2_t*(dx_t[k]*dx_t[l]/2)
//   S3[ij,k]  = sum_t v2_t*dx_t[k]
// Structure = R13 (best, 38.7us): two K=64 GEMM passes, U2 carried bf16 in
// VGPRs across pass 0 (single serial build), direct epilogue.
// R15 deltas:
//  (1) nontemporal epilogue stores — R14 proved write amplification
//      (89->110 MB) is L2 residency at >=4 blocks/CU, not store pattern;
//      nt bypasses L2 for the write-once output (no write-allocate/RMW).
//  (2) LDS 33.5 -> 31.7 KB (DXP 13->11, odd stride = still bank-permuting)
//      + __launch_bounds__(256,5) -> 5 blocks/CU latency-hiding pool.

typedef short short8 __attribute__((ext_vector_type(8)));
typedef float f32x4 __attribute__((ext_vector_type(4)));
typedef unsigned int uint4v __attribute__((ext_vector_type(4)));

constexpr int C = 10, L = 64, T = 63;          // T = L-1 steps
constexpr int OUTSZ = 10 + 100 + 1000 + 10000; // 11110
constexpr int DXP = 11;                        // dx/P row stride (fp32 words, odd)
constexpr int KS = 64;                         // per-pass row stride in shorts (128B)

__device__ __forceinline__ unsigned short f2bf(float f) {  // RNE f32->bf16
  unsigned u = __float_as_uint(f);
  return (unsigned short)((u + 0x7FFFu + ((u >> 16) & 1u)) >> 16);
}
__device__ __forceinline__ int swz(int row, int k) {  // short idx, 16B-granule XOR
  return row * KS + ((((k >> 3) ^ (row & 7)) << 3) | (k & 7));
}

__global__ __launch_bounds__(256, 5) void sig4_kernel(
    const float* __restrict__ x, float* __restrict__ out)
{
  __shared__ __align__(16) unsigned char smem_raw[32480];
  unsigned short* Ab = (unsigned short*)smem_raw;            // 100*64 sh = 12800B
  unsigned short* Bb = (unsigned short*)(smem_raw + 12800);  // 110*64 sh = 14080B
  float* dxs = (float*)(smem_raw + 26880);                   // 63*11 f = 2772B
  float* Ps  = (float*)(smem_raw + 29652);                   // 64*11 f = 2816B

  const int t = threadIdx.x;
  const float* __restrict__ xb = x + (size_t)blockIdx.x * (C * L);
  float* __restrict__ ob = out + (size_t)blockIdx.x * OUTSZ;

  // ---- phase A: path -> dx, exclusive prefix P (shuffle scan) ----
  float* pl = (float*)Bb;  // alias: Bb first written in build (after last pl read)
  for (int i = t; i < C * L; i += 256) pl[i] = xb[i];
  __syncthreads();
  for (int i = t; i < T * C; i += 256) {
    int s = i / C, c = i - s * C;
    dxs[s * DXP + c] = pl[c * L + s + 1] - pl[c * L + s];
  }
  __syncthreads();
  {
    int w0 = t >> 6, lane0 = t & 63;
    for (int c = w0; c < C; c += 4) {
      float v = (lane0 > 0) ? dxs[(lane0 - 1) * DXP + c] : 0.f;
      #pragma unroll
      for (int d = 1; d < 64; d <<= 1) {
        float y = __shfl_up(v, d);
        if (lane0 >= d) v += y;
      }
      Ps[lane0 * DXP + c] = v;  // P[t][c] = sum_{s<t} dx_s[c]; P[63] = S1
    }
  }
  __syncthreads();

  unsigned u2r[32];  // U2 bf16-packed (64 slots; slot 63 zero), static-indexed

  // ---- build pass 0: A=V2 (lanes 0..99) || B=[dx ox R | dx] (lanes 128..255) ----
  if (t < 100) {
    const int i_ = t / 10, j_ = t - (t / 10) * 10;
    float s2 = 0.f;
    #pragma unroll
    for (int ch = 0; ch < 8; ++ch) {
      unsigned vpk[4];
      #pragma unroll
      for (int e = 0; e < 8; ++e) {
        const int s = ch * 8 + e;
        float u2 = 0.f, v2 = 0.f;
        if (s < T) {
          float di = dxs[s * DXP + i_];
          float dj = dxs[s * DXP + j_];
          float p  = Ps[s * DXP + i_];
          u2 = fmaf(fmaf(di, 0.25f, p), dj * (1.f / 3.f), s2);
          v2 = fmaf(fmaf(di, (1.f / 3.f), p), dj * 0.5f, s2);
          s2 = fmaf(fmaf(di, 0.5f, p), dj, s2);
        }
        unsigned vb = f2bf(v2), ub = f2bf(u2);
        if ((e & 1) == 0) { vpk[e >> 1] = vb;        u2r[ch * 4 + (e >> 1)] = ub; }
        else             { vpk[e >> 1] |= vb << 16;  u2r[ch * 4 + (e >> 1)] |= ub << 16; }
      }
      *(uint4v*)&Ab[swz(t, ch * 8)] = uint4v{vpk[0], vpk[1], vpk[2], vpk[3]};
    }
    ob[10 + t] = s2;                            // S2 (exact fp32)
    if (j_ == 0) ob[i_] = Ps[63 * DXP + i_];    // S1
  } else if (t >= 128) {
    const int q = t - 128;
    for (int task = q; task < 110 * 8; task += 128) {
      const int col = task >> 3, ch = task & 7;
      unsigned pk[4];
      if (col < 100) {
        const int k2 = col / 10, l2 = col - (col / 10) * 10;
        const float S1l = Ps[63 * DXP + l2];
        #pragma unroll
        for (int e = 0; e < 8; ++e) {
          const int kk = ch * 8 + e;
          float b1 = 0.f;
          if (kk < T) {
            float d = dxs[kk * DXP + k2];
            b1 = d * (S1l - Ps[(kk + 1) * DXP + l2]);
          }
          unsigned x1 = f2bf(b1);
          if ((e & 1) == 0) pk[e >> 1] = x1; else pk[e >> 1] |= x1 << 16;
        }
      } else {
        const int c2 = col - 100;
        #pragma unroll
        for (int e = 0; e < 8; ++e) {
          const int kk = ch * 8 + e;
          float b1 = (kk < T) ? dxs[kk * DXP + c2] : 0.f;
          unsigned x1 = f2bf(b1);
          if ((e & 1) == 0) pk[e >> 1] = x1; else pk[e >> 1] |= x1 << 16;
        }
      }
      *(uint4v*)&Bb[swz(col, ch * 8)] = uint4v{pk[0], pk[1], pk[2], pk[3]};
    }
  }
  __syncthreads();

  const int w = t >> 6, lane = t & 63;
  const int lm = lane & 15, lg = lane >> 4;

  f32x4 acc[2][7];
  #pragma unroll
  for (int rti = 0; rti < 2; ++rti)
    #pragma unroll
    for (int ct = 0; ct < 7; ++ct) acc[rti][ct] = f32x4{0.f, 0.f, 0.f, 0.f};

  // ---- GEMM (B fragments reused across both rt strips) ----
  #define GEMM_PASS()                                                          \
    do {                                                                       \
      short8 afr[2][2];                                                        \
      _Pragma("unroll")                                                        \
      for (int rti = 0; rti < 2; ++rti) {                                      \
        const int rt = w + rti * 4;                                            \
        const int arow = rt * 16 + lm;                                         \
        _Pragma("unroll")                                                      \
        for (int ks = 0; ks < 2; ++ks)                                         \
          afr[rti][ks] = (rt < 7 && arow < 100)                                \
              ? *(const short8*)&Ab[swz(arow, ks * 32 + lg * 8)]               \
              : short8{0, 0, 0, 0, 0, 0, 0, 0};                                \
      }                                                                        \
      for (int ct = 0; ct < 7; ++ct) {                                         \
        const int bcol = ct * 16 + lm;                                         \
        short8 b0 = (bcol < 110) ? *(const short8*)&Bb[swz(bcol, lg * 8)]      \
                                 : short8{0, 0, 0, 0, 0, 0, 0, 0};             \
        short8 b1 = (bcol < 110) ? *(const short8*)&Bb[swz(bcol, 32 + lg * 8)] \
                                 : short8{0, 0, 0, 0, 0, 0, 0, 0};             \
        _Pragma("unroll")                                                      \
        for (int rti = 0; rti < 2; ++rti) {                                    \
          if (w + rti * 4 < 7) {                                               \
            acc[rti][ct] = __builtin_amdgcn_mfma_f32_16x16x32_bf16(            \
                afr[rti][0], b0, acc[rti][ct], 0, 0, 0);                       \
            acc[rti][ct] = __builtin_amdgcn_mfma_f32_16x16x32_bf16(            \
                afr[rti][1], b1, acc[rti][ct], 0, 0, 0);                       \
          }                                                                    \
        }                                                                      \
      }                                                                        \
    } while (0)

  GEMM_PASS();   // pass 0: V2 x [dx ox R | dx]
  __syncthreads();

  // ---- build pass 1: A=U2 from registers || B=[dx ox dx /2 | 0] ----
  if (t < 100) {
    #pragma unroll
    for (int ch = 0; ch < 8; ++ch)
      *(uint4v*)&Ab[swz(t, ch * 8)] = uint4v{u2r[ch * 4], u2r[ch * 4 + 1],
                                             u2r[ch * 4 + 2], u2r[ch * 4 + 3]};
  } else if (t >= 128) {
    const int q = t - 128;
    for (int task = q; task < 110 * 8; task += 128) {
      const int col = task >> 3, ch = task & 7;
      unsigned pk[4] = {0u, 0u, 0u, 0u};
      if (col < 100) {
        const int k2 = col / 10, l2 = col - (col / 10) * 10;
        #pragma unroll
        for (int e = 0; e < 8; ++e) {
          const int kk = ch * 8 + e;
          float b2 = (kk < T) ? dxs[kk * DXP + k2] * dxs[kk * DXP + l2] * 0.5f : 0.f;
          unsigned x2 = f2bf(b2);
          if ((e & 1) == 0) pk[e >> 1] = x2; else pk[e >> 1] |= x2 << 16;
        }
      }
      *(uint4v*)&Bb[swz(col, ch * 8)] = uint4v{pk[0], pk[1], pk[2], pk[3]};
    }
  }
  __syncthreads();

  GEMM_PASS();   // pass 1: U2 x [dx ox dx /2 | 0], accumulates

  // ---- epilogue: direct NONTEMPORAL stores (write-once output, skip L2) ----
  #pragma unroll
  for (int rti = 0; rti < 2; ++rti) {
    const int rt = w + rti * 4;
    if (rt < 7) {
      const int rbase = rt * 16 + lg * 4;
      #pragma unroll
      for (int ct = 0; ct < 7; ++ct) {
        const int bcol = ct * 16 + lm;
        #pragma unroll
        for (int r = 0; r < 4; ++r) {
          const int row = rbase + r;
          if (row < 100) {
            if (bcol < 100)
              __builtin_nontemporal_store(acc[rti][ct][r],
                                          &ob[1110 + row * 100 + bcol]);
            else if (bcol < 110)
              __builtin_nontemporal_store(acc[rti][ct][r],
                                          &ob[110 + row * 10 + (bcol - 100)]);
          }
        }
      }
    }
  }
}

extern "C" void kernel_launch(void* const* d_in, const int* in_sizes, int n_in,
                              void* d_out, int out_size, void* d_ws, size_t ws_size,
                              hipStream_t stream) {
  const float* x = (const float*)d_in[0];
  float* out = (float*)d_out;
  const int batch = in_sizes[0] / (C * L);   // 2048
  sig4_kernel<<<dim3(batch), dim3(256), 0, stream>>>(x, out);
}

// Round 16
// 39.522 us; speedup vs baseline: 2.7502x; 2.7502x over previous
//
#include <hip/hip_runtime.h>

// Depth-4 path signature, C=10, L=64, B=2048 — MFMA formulation (R16).
// Closed form (validated R8-R15, absmax 5.25 vs thr 12.16):
//   P_t = exclusive prefix of dx;  R_t[l] = S1[l] - P_{t+1}[l]
//   per (i,j): s2 serial chain; u2_t, v2_t level-2 scalars
//   S4[ij,kl] = sum_t v2_t*(dx_t[k]*R_t[l]) + sum_t u2_t*(dx_t[k]*dx_t[l]/2)
//   S3[ij,k]  = sum_t v2_t*dx_t[k]
// Structure = R13 (best, 38.7us): two K=64 GEMM passes, U2 carried bf16 in
// VGPRs across pass 0, direct scattered epilogue (L2 combines; R15 proved
// nontemporal scalar stores bypass combining -> 303MB written, NEVER again).
// R16 deltas:
//  (1) A-build chain shortened 3x: z/bu/bv computed pointwise (ILP), serial
//      part reduced to one dependent add per step (s2 += z[e]).
//  (2) DXP 13 -> 11: LDS 33.8 -> 32.5KB raw (alloc 32KB) -> 5 blocks/CU
//      becomes feasible; launch_bounds stays (256,4) for regalloc headroom.

typedef short short8 __attribute__((ext_vector_type(8)));
typedef float f32x4 __attribute__((ext_vector_type(4)));
typedef unsigned int uint4v __attribute__((ext_vector_type(4)));

constexpr int C = 10, L = 64, T = 63;          // T = L-1 steps
constexpr int OUTSZ = 10 + 100 + 1000 + 10000; // 11110
constexpr int DXP = 11;                        // dx/P row stride (fp32 words, odd)
constexpr int KS = 64;                         // per-pass row stride in shorts (128B)

__device__ __forceinline__ unsigned short f2bf(float f) {  // RNE f32->bf16
  unsigned u = __float_as_uint(f);
  return (unsigned short)((u + 0x7FFFu + ((u >> 16) & 1u)) >> 16);
}
__device__ __forceinline__ int swz(int row, int k) {  // short idx, 16B-granule XOR
  return row * KS + ((((k >> 3) ^ (row & 7)) << 3) | (k & 7));
}

__global__ __launch_bounds__(256, 4) void sig4_kernel(
    const float* __restrict__ x, float* __restrict__ out)
{
  __shared__ __align__(16) unsigned char smem_raw[32480];
  unsigned short* Ab = (unsigned short*)smem_raw;            // 100*64 sh = 12800B
  unsigned short* Bb = (unsigned short*)(smem_raw + 12800);  // 110*64 sh = 14080B
  float* dxs = (float*)(smem_raw + 26880);                   // 63*11 f = 2772B
  float* Ps  = (float*)(smem_raw + 29652);                   // 64*11 f = 2816B

  const int t = threadIdx.x;
  const float* __restrict__ xb = x + (size_t)blockIdx.x * (C * L);
  float* __restrict__ ob = out + (size_t)blockIdx.x * OUTSZ;

  // ---- phase A: path -> dx, exclusive prefix P (shuffle scan) ----
  float* pl = (float*)Bb;  // alias: Bb first written in build (after last pl read)
  for (int i = t; i < C * L; i += 256) pl[i] = xb[i];
  __syncthreads();
  for (int i = t; i < T * C; i += 256) {
    int s = i / C, c = i - s * C;
    dxs[s * DXP + c] = pl[c * L + s + 1] - pl[c * L + s];
  }
  __syncthreads();
  {
    int w0 = t >> 6, lane0 = t & 63;
    for (int c = w0; c < C; c += 4) {
      float v = (lane0 > 0) ? dxs[(lane0 - 1) * DXP + c] : 0.f;
      #pragma unroll
      for (int d = 1; d < 64; d <<= 1) {
        float y = __shfl_up(v, d);
        if (lane0 >= d) v += y;
      }
      Ps[lane0 * DXP + c] = v;  // P[t][c] = sum_{s<t} dx_s[c]; P[63] = S1
    }
  }
  __syncthreads();

  unsigned u2r[32];  // U2 bf16-packed (64 slots; slot 63 zero), static-indexed

  // ---- build pass 0: A=V2 (lanes 0..99) || B=[dx ox R | dx] (lanes 128..255) ----
  if (t < 100) {
    const int i_ = t / 10, j_ = t - (t / 10) * 10;
    float s2 = 0.f;
    #pragma unroll
    for (int ch = 0; ch < 8; ++ch) {
      // pointwise (ILP-friendly): z, bu, bv for 8 steps
      float zz[8], bu[8], bv[8];
      #pragma unroll
      for (int e = 0; e < 8; ++e) {
        const int s = ch * 8 + e;
        if (s < T) {
          float di = dxs[s * DXP + i_];
          float dj = dxs[s * DXP + j_];
          float p  = Ps[s * DXP + i_];
          bu[e] = fmaf(di, 0.25f, p) * (dj * (1.f / 3.f));
          bv[e] = fmaf(di, (1.f / 3.f), p) * (dj * 0.5f);
          zz[e] = fmaf(di, 0.5f, p) * dj;
        } else {
          bu[e] = 0.f; bv[e] = 0.f; zz[e] = 0.f;
        }
      }
      // serial part: one dependent add per step
      unsigned vpk[4];
      #pragma unroll
      for (int e = 0; e < 8; ++e) {
        float u2 = bu[e] + s2;
        float v2 = bv[e] + s2;
        s2 += zz[e];
        unsigned vb = f2bf(v2), ub = f2bf(u2);
        if ((e & 1) == 0) { vpk[e >> 1] = vb;        u2r[ch * 4 + (e >> 1)] = ub; }
        else             { vpk[e >> 1] |= vb << 16;  u2r[ch * 4 + (e >> 1)] |= ub << 16; }
      }
      *(uint4v*)&Ab[swz(t, ch * 8)] = uint4v{vpk[0], vpk[1], vpk[2], vpk[3]};
    }
    ob[10 + t] = s2;                            // S2 (fp32)
    if (j_ == 0) ob[i_] = Ps[63 * DXP + i_];    // S1
  } else if (t >= 128) {
    const int q = t - 128;
    for (int task = q; task < 110 * 8; task += 128) {
      const int col = task >> 3, ch = task & 7;
      unsigned pk[4];
      if (col < 100) {
        const int k2 = col / 10, l2 = col - (col / 10) * 10;
        const float S1l = Ps[63 * DXP + l2];
        #pragma unroll
        for (int e = 0; e < 8; ++e) {
          const int kk = ch * 8 + e;
          float b1 = 0.f;
          if (kk < T) {
            float d = dxs[kk * DXP + k2];
            b1 = d * (S1l - Ps[(kk + 1) * DXP + l2]);
          }
          unsigned x1 = f2bf(b1);
          if ((e & 1) == 0) pk[e >> 1] = x1; else pk[e >> 1] |= x1 << 16;
        }
      } else {
        const int c2 = col - 100;
        #pragma unroll
        for (int e = 0; e < 8; ++e) {
          const int kk = ch * 8 + e;
          float b1 = (kk < T) ? dxs[kk * DXP + c2] : 0.f;
          unsigned x1 = f2bf(b1);
          if ((e & 1) == 0) pk[e >> 1] = x1; else pk[e >> 1] |= x1 << 16;
        }
      }
      *(uint4v*)&Bb[swz(col, ch * 8)] = uint4v{pk[0], pk[1], pk[2], pk[3]};
    }
  }
  __syncthreads();

  const int w = t >> 6, lane = t & 63;
  const int lm = lane & 15, lg = lane >> 4;

  f32x4 acc[2][7];
  #pragma unroll
  for (int rti = 0; rti < 2; ++rti)
    #pragma unroll
    for (int ct = 0; ct < 7; ++ct) acc[rti][ct] = f32x4{0.f, 0.f, 0.f, 0.f};

  // ---- GEMM (B fragments reused across both rt strips) ----
  #define GEMM_PASS()                                                          \
    do {                                                                       \
      short8 afr[2][2];                                                        \
      _Pragma("unroll")                                                        \
      for (int rti = 0; rti < 2; ++rti) {                                      \
        const int rt = w + rti * 4;                                            \
        const int arow = rt * 16 + lm;                                         \
        _Pragma("unroll")                                                      \
        for (int ks = 0; ks < 2; ++ks)                                         \
          afr[rti][ks] = (rt < 7 && arow < 100)                                \
              ? *(const short8*)&Ab[swz(arow, ks * 32 + lg * 8)]               \
              : short8{0, 0, 0, 0, 0, 0, 0, 0};                                \
      }                                                                        \
      for (int ct = 0; ct < 7; ++ct) {                                         \
        const int bcol = ct * 16 + lm;                                         \
        short8 b0 = (bcol < 110) ? *(const short8*)&Bb[swz(bcol, lg * 8)]      \
                                 : short8{0, 0, 0, 0, 0, 0, 0, 0};             \
        short8 b1 = (bcol < 110) ? *(const short8*)&Bb[swz(bcol, 32 + lg * 8)] \
                                 : short8{0, 0, 0, 0, 0, 0, 0, 0};             \
        _Pragma("unroll")                                                      \
        for (int rti = 0; rti < 2; ++rti) {                                    \
          if (w + rti * 4 < 7) {                                               \
            acc[rti][ct] = __builtin_amdgcn_mfma_f32_16x16x32_bf16(            \
                afr[rti][0], b0, acc[rti][ct], 0, 0, 0);                       \
            acc[rti][ct] = __builtin_amdgcn_mfma_f32_16x16x32_bf16(            \
                afr[rti][1], b1, acc[rti][ct], 0, 0, 0);                       \
          }                                                                    \
        }                                                                      \
      }                                                                        \
    } while (0)

  GEMM_PASS();   // pass 0: V2 x [dx ox R | dx]
  __syncthreads();

  // ---- build pass 1: A=U2 from registers || B=[dx ox dx /2 | 0] ----
  if (t < 100) {
    #pragma unroll
    for (int ch = 0; ch < 8; ++ch)
      *(uint4v*)&Ab[swz(t, ch * 8)] = uint4v{u2r[ch * 4], u2r[ch * 4 + 1],
                                             u2r[ch * 4 + 2], u2r[ch * 4 + 3]};
  } else if (t >= 128) {
    const int q = t - 128;
    for (int task = q; task < 110 * 8; task += 128) {
      const int col = task >> 3, ch = task & 7;
      unsigned pk[4] = {0u, 0u, 0u, 0u};
      if (col < 100) {
        const int k2 = col / 10, l2 = col - (col / 10) * 10;
        #pragma unroll
        for (int e = 0; e < 8; ++e) {
          const int kk = ch * 8 + e;
          float b2 = (kk < T) ? dxs[kk * DXP + k2] * dxs[kk * DXP + l2] * 0.5f : 0.f;
          unsigned x2 = f2bf(b2);
          if ((e & 1) == 0) pk[e >> 1] = x2; else pk[e >> 1] |= x2 << 16;
        }
      }
      *(uint4v*)&Bb[swz(col, ch * 8)] = uint4v{pk[0], pk[1], pk[2], pk[3]};
    }
  }
  __syncthreads();

  GEMM_PASS();   // pass 1: U2 x [dx ox dx /2 | 0], accumulates

  // ---- epilogue: direct scattered stores (L2 write-combining handles it) ----
  #pragma unroll
  for (int rti = 0; rti < 2; ++rti) {
    const int rt = w + rti * 4;
    if (rt < 7) {
      const int rbase = rt * 16 + lg * 4;
      #pragma unroll
      for (int ct = 0; ct < 7; ++ct) {
        const int bcol = ct * 16 + lm;
        #pragma unroll
        for (int r = 0; r < 4; ++r) {
          const int row = rbase + r;
          if (row < 100) {
            if (bcol < 100)      ob[1110 + row * 100 + bcol] = acc[rti][ct][r];
            else if (bcol < 110) ob[110 + row * 10 + (bcol - 100)] = acc[rti][ct][r];
          }
        }
      }
    }
  }
}

extern "C" void kernel_launch(void* const* d_in, const int* in_sizes, int n_in,
                              void* d_out, int out_size, void* d_ws, size_t ws_size,
                              hipStream_t stream) {
  const float* x = (const float*)d_in[0];
  float* out = (float*)d_out;
  const int batch = in_sizes[0] / (C * L);   // 2048
  sig4_kernel<<<dim3(batch), dim3(256), 0, stream>>>(x, out);
}

// Round 17
// 38.482 us; speedup vs baseline: 2.8245x; 1.0270x over previous
//
#include <hip/hip_runtime.h>
#include <hip/hip_bf16.h>

// Depth-4 path signature, C=10, L=64, B=2048 — MFMA formulation (R17).
// Closed form (validated R8-R16, absmax 5.25 vs thr 12.16):
//   P_t = exclusive prefix of dx;  R_t[l] = S1[l] - P_{t+1}[l]
//   per (i,j): s2 serial chain; u2_t, v2_t level-2 scalars
//   S4[ij,kl] = sum_t v2_t*(dx_t[k]*R_t[l]) + sum_t u2_t*(dx_t[k]*dx_t[l]/2)
//   S3[ij,k]  = sum_t v2_t*dx_t[k]
// Structure = R13/R16: two K=64 GEMM passes, U2 carried bf16-packed in VGPRs.
// R17 deltas (instruction diet; VALU-busy was ~17us of 39.5us wall):
//  (1) v_cvt_pk_bf16_f32 via __float22bfloat162_rn replaces manual RNE
//      bit-math (+pack) in A/B builds: ~7 insts/value -> ~0.5.
//  (2) MFMA operands SWAPPED -> C transposed: lane now holds 4 consecutive
//      output COLUMNS of one row (reg dim), so the epilogue is 2x f2 stores
//      per tile (28 vs 56 insts, 1/4 the address math). A/B fragment lane
//      addressing is symmetric (idx=lane&15, kblk=lane>>4), so swapping is
//      an exact transpose of the verified layout.

typedef short short8 __attribute__((ext_vector_type(8)));
typedef float f2 __attribute__((ext_vector_type(2)));
typedef float f32x4 __attribute__((ext_vector_type(4)));
typedef unsigned int uint4v __attribute__((ext_vector_type(4)));

constexpr int C = 10, L = 64, T = 63;          // T = L-1 steps
constexpr int OUTSZ = 10 + 100 + 1000 + 10000; // 11110
constexpr int DXP = 11;                        // dx/P row stride (fp32 words, odd)
constexpr int KS = 64;                         // per-pass row stride in shorts (128B)

__device__ __forceinline__ unsigned packbf(float lo, float hi) {  // v_cvt_pk_bf16_f32
  union { __hip_bfloat162 h; unsigned u; } cv;
  cv.h = __float22bfloat162_rn(make_float2(lo, hi));
  return cv.u;
}
__device__ __forceinline__ int swz(int row, int k) {  // short idx, 16B-granule XOR
  return row * KS + ((((k >> 3) ^ (row & 7)) << 3) | (k & 7));
}

__global__ __launch_bounds__(256, 4) void sig4_kernel(
    const float* __restrict__ x, float* __restrict__ out)
{
  __shared__ __align__(16) unsigned char smem_raw[32480];
  unsigned short* Ab = (unsigned short*)smem_raw;            // 100*64 sh = 12800B
  unsigned short* Bb = (unsigned short*)(smem_raw + 12800);  // 110*64 sh = 14080B
  float* dxs = (float*)(smem_raw + 26880);                   // 63*11 f = 2772B
  float* Ps  = (float*)(smem_raw + 29652);                   // 64*11 f = 2816B

  const int t = threadIdx.x;
  const float* __restrict__ xb = x + (size_t)blockIdx.x * (C * L);
  float* __restrict__ ob = out + (size_t)blockIdx.x * OUTSZ;

  // ---- phase A: path -> dx, exclusive prefix P (shuffle scan) ----
  float* pl = (float*)Bb;  // alias: Bb first written in build (after last pl read)
  for (int i = t; i < C * L; i += 256) pl[i] = xb[i];
  __syncthreads();
  for (int i = t; i < T * C; i += 256) {
    int s = i / C, c = i - s * C;
    dxs[s * DXP + c] = pl[c * L + s + 1] - pl[c * L + s];
  }
  __syncthreads();
  {
    int w0 = t >> 6, lane0 = t & 63;
    for (int c = w0; c < C; c += 4) {
      float v = (lane0 > 0) ? dxs[(lane0 - 1) * DXP + c] : 0.f;
      #pragma unroll
      for (int d = 1; d < 64; d <<= 1) {
        float y = __shfl_up(v, d);
        if (lane0 >= d) v += y;
      }
      Ps[lane0 * DXP + c] = v;  // P[t][c] = sum_{s<t} dx_s[c]; P[63] = S1
    }
  }
  __syncthreads();

  unsigned u2r[32];  // U2 bf16-packed (64 slots; slot 63 zero), static-indexed

  // ---- build pass 0: A=V2 (lanes 0..99) || B=[dx ox R | dx] (lanes 128..255) ----
  if (t < 100) {
    const int i_ = t / 10, j_ = t - (t / 10) * 10;
    float s2 = 0.f;
    #pragma unroll
    for (int ch = 0; ch < 8; ++ch) {
      float bu[8], bv[8], zz[8];
      #pragma unroll
      for (int e = 0; e < 8; ++e) {      // pointwise, ILP-friendly
        const int s = ch * 8 + e;
        if (s < T) {
          float di = dxs[s * DXP + i_];
          float dj = dxs[s * DXP + j_];
          float p  = Ps[s * DXP + i_];
          bu[e] = fmaf(di, 0.25f, p) * (dj * (1.f / 3.f));
          bv[e] = fmaf(di, (1.f / 3.f), p) * (dj * 0.5f);
          zz[e] = fmaf(di, 0.5f, p) * dj;
        } else { bu[e] = 0.f; bv[e] = 0.f; zz[e] = 0.f; }
      }
      float u2v[8], v2v[8];
      #pragma unroll
      for (int e = 0; e < 8; ++e) {      // serial part: 1 dependent add/step
        u2v[e] = bu[e] + s2;
        v2v[e] = bv[e] + s2;
        s2 += zz[e];
      }
      uint4v vp;
      #pragma unroll
      for (int q = 0; q < 4; ++q) {
        vp[q] = packbf(v2v[2 * q], v2v[2 * q + 1]);
        u2r[ch * 4 + q] = packbf(u2v[2 * q], u2v[2 * q + 1]);
      }
      *(uint4v*)&Ab[swz(t, ch * 8)] = vp;
    }
    ob[10 + t] = s2;                            // S2 (fp32)
    if (j_ == 0) ob[i_] = Ps[63 * DXP + i_];    // S1
  } else if (t >= 128) {
    const int q = t - 128;
    for (int task = q; task < 110 * 8; task += 128) {
      const int col = task >> 3, ch = task & 7;
      float b1v[8];
      if (col < 100) {
        const int k2 = col / 10, l2 = col - (col / 10) * 10;
        const float S1l = Ps[63 * DXP + l2];
        #pragma unroll
        for (int e = 0; e < 8; ++e) {
          const int kk = ch * 8 + e;
          b1v[e] = (kk < T)
              ? dxs[kk * DXP + k2] * (S1l - Ps[(kk + 1) * DXP + l2]) : 0.f;
        }
      } else {
        const int c2 = col - 100;
        #pragma unroll
        for (int e = 0; e < 8; ++e) {
          const int kk = ch * 8 + e;
          b1v[e] = (kk < T) ? dxs[kk * DXP + c2] : 0.f;
        }
      }
      uint4v pk;
      #pragma unroll
      for (int qq = 0; qq < 4; ++qq) pk[qq] = packbf(b1v[2 * qq], b1v[2 * qq + 1]);
      *(uint4v*)&Bb[swz(col, ch * 8)] = pk;
    }
  }
  __syncthreads();

  const int w = t >> 6, lane = t & 63;
  const int lm = lane & 15, lg = lane >> 4;

  f32x4 acc[2][7];
  #pragma unroll
  for (int rti = 0; rti < 2; ++rti)
    #pragma unroll
    for (int ct = 0; ct < 7; ++ct) acc[rti][ct] = f32x4{0.f, 0.f, 0.f, 0.f};

  // ---- GEMM, operands swapped -> transposed C (B reused across rt strips) ----
  #define GEMM_PASS()                                                          \
    do {                                                                       \
      short8 afr[2][2];                                                        \
      _Pragma("unroll")                                                        \
      for (int rti = 0; rti < 2; ++rti) {                                      \
        const int rt = w + rti * 4;                                            \
        const int arow = rt * 16 + lm;                                         \
        _Pragma("unroll")                                                      \
        for (int ks = 0; ks < 2; ++ks)                                         \
          afr[rti][ks] = (rt < 7 && arow < 100)                                \
              ? *(const short8*)&Ab[swz(arow, ks * 32 + lg * 8)]               \
              : short8{0, 0, 0, 0, 0, 0, 0, 0};                                \
      }                                                                        \
      for (int ct = 0; ct < 7; ++ct) {                                         \
        const int bcol = ct * 16 + lm;                                         \
        short8 b0 = (bcol < 110) ? *(const short8*)&Bb[swz(bcol, lg * 8)]      \
                                 : short8{0, 0, 0, 0, 0, 0, 0, 0};             \
        short8 b1 = (bcol < 110) ? *(const short8*)&Bb[swz(bcol, 32 + lg * 8)] \
                                 : short8{0, 0, 0, 0, 0, 0, 0, 0};             \
        _Pragma("unroll")                                                      \
        for (int rti = 0; rti < 2; ++rti) {                                    \
          if (w + rti * 4 < 7) {                                               \
            acc[rti][ct] = __builtin_amdgcn_mfma_f32_16x16x32_bf16(            \
                b0, afr[rti][0], acc[rti][ct], 0, 0, 0);                       \
            acc[rti][ct] = __builtin_amdgcn_mfma_f32_16x16x32_bf16(            \
                b1, afr[rti][1], acc[rti][ct], 0, 0, 0);                       \
          }                                                                    \
        }                                                                      \
      }                                                                        \
    } while (0)

  GEMM_PASS();   // pass 0: V2 x [dx ox R | dx]
  __syncthreads();

  // ---- build pass 1: A=U2 from registers || B=[dx ox dx /2 | 0] ----
  if (t < 100) {
    #pragma unroll
    for (int ch = 0; ch < 8; ++ch)
      *(uint4v*)&Ab[swz(t, ch * 8)] = uint4v{u2r[ch * 4], u2r[ch * 4 + 1],
                                             u2r[ch * 4 + 2], u2r[ch * 4 + 3]};
  } else if (t >= 128) {
    const int q = t - 128;
    for (int task = q; task < 110 * 8; task += 128) {
      const int col = task >> 3, ch = task & 7;
      float b2v[8] = {0.f, 0.f, 0.f, 0.f, 0.f, 0.f, 0.f, 0.f};
      if (col < 100) {
        const int k2 = col / 10, l2 = col - (col / 10) * 10;
        #pragma unroll
        for (int e = 0; e < 8; ++e) {
          const int kk = ch * 8 + e;
          b2v[e] = (kk < T) ? dxs[kk * DXP + k2] * dxs[kk * DXP + l2] * 0.5f : 0.f;
        }
      }
      uint4v pk;
      #pragma unroll
      for (int qq = 0; qq < 4; ++qq) pk[qq] = packbf(b2v[2 * qq], b2v[2 * qq + 1]);
      *(uint4v*)&Bb[swz(col, ch * 8)] = pk;
    }
  }
  __syncthreads();

  GEMM_PASS();   // pass 1: U2 x [dx ox dx /2 | 0], accumulates

  // ---- epilogue: transposed acc -> per-lane contiguous f2 stores ----
  #pragma unroll
  for (int rti = 0; rti < 2; ++rti) {
    const int rt = w + rti * 4;
    if (rt < 7) {
      const int row = rt * 16 + lm;        // output ij-row
      if (row < 100) {
        float* rowp4 = ob + 1110 + row * 100;
        float* rowp3 = ob + 110 + row * 10;
        #pragma unroll
        for (int ct = 0; ct < 7; ++ct) {
          const int colbase = ct * 16 + lg * 4;   // output col (4 consecutive)
          f2 lo = {acc[rti][ct][0], acc[rti][ct][1]};
          f2 hi = {acc[rti][ct][2], acc[rti][ct][3]};
          if (colbase < 100) {                    // colbase <= 96 -> +3 <= 99
            *(f2*)(rowp4 + colbase) = lo;
            *(f2*)(rowp4 + colbase + 2) = hi;
          } else if (colbase < 110) {             // 100 / 104 / 108 -> S3
            *(f2*)(rowp3 + (colbase - 100)) = lo;
            if (colbase < 108) *(f2*)(rowp3 + (colbase - 98)) = hi;
          }
        }
      }
    }
  }
}

extern "C" void kernel_launch(void* const* d_in, const int* in_sizes, int n_in,
                              void* d_out, int out_size, void* d_ws, size_t ws_size,
                              hipStream_t stream) {
  const float* x = (const float*)d_in[0];
  float* out = (float*)d_out;
  const int batch = in_sizes[0] / (C * L);   // 2048
  sig4_kernel<<<dim3(batch), dim3(256), 0, stream>>>(x, out);
}